// Round 10
// baseline (524.508 us; speedup 1.0000x reference)
//
#include <hip/hip_runtime.h>
#include <hip/hip_bf16.h>
#include <math.h>

#define Gn 16000
#define Bn 4096
#define Ln 64
#define Sn 20000

typedef __attribute__((ext_vector_type(8))) short bf16x8;   // 8 bf16 = 4 VGPRs
typedef __attribute__((ext_vector_type(4))) float f32x4;    // MFMA C/D

#define LN2  0.6931471805599453f
#define RLN2 1.4426950408889634f

// ---------- device math helpers ----------

__device__ __forceinline__ float softplus_precise(float z) {
    return fmaxf(z, 0.0f) + log1pf(__expf(-fabsf(z)));
}

// raw v_log_f32 = log2(x); args always normal (>= ~5) so libm fixups skipped
__device__ __forceinline__ float raw_log2(float v) {
    float r;
    asm("v_log_f32 %0, %1" : "=v"(r) : "v"(v));
    return r;
}

// accurate lgamma for z>0 (shift-8 Stirling), used only for the 100-entry table
__device__ __forceinline__ float lgamma_pos8(float z) {
    float p = z * (z + 1.f) * (z + 2.f) * (z + 3.f)
                * (z + 4.f) * (z + 5.f) * (z + 6.f) * (z + 7.f);
    float w = z + 8.f;
    return (w - 0.5f) * __logf(w) - w + 0.9189385332046727f
           + __fdividef(1.0f, 12.0f * w) - __logf(p);
}

__device__ __forceinline__ unsigned short f2bf(float f) {
    union { float f; unsigned int u; } v; v.f = f;
    unsigned int r = v.u + 0x7fff + ((v.u >> 16) & 1);   // RNE
    return (unsigned short)(r >> 16);
}

// ---------- x packing: int32 [0,100) -> uint8, pure-streaming copy shape ----------
// 16000 blocks x 256 thr; each thread 4 int4 loads + 4 dword stores, all
// instruction-coalesced (consecutive lanes -> consecutive addresses).

__global__ __launch_bounds__(256) void pack_x(const int* __restrict__ x,
                                              unsigned int* __restrict__ x8) {
    const int base = blockIdx.x * 1024 + threadIdx.x;   // int4-group index
    #pragma unroll
    for (int k = 0; k < 4; k++) {
        const int idx = base + k * 256;
        const int4 v = ((const int4*)x)[idx];
        x8[idx] = (unsigned)(v.x & 0xff) | ((unsigned)(v.y & 0xff) << 8)
                | ((unsigned)(v.z & 0xff) << 16) | ((unsigned)(v.w & 0xff) << 24);
    }
}

// ---------- precompute kernels ----------
//
// GENE PERMUTATION (as r7): within each 64-gene block, gene j = ln*4 + nb is
// stored at MFMA column c = (j&3)*16 + (j>>2), so each lane's 4 output
// columns are 4 consecutive genes -> x/consts load as one dword/dwordx4.

__global__ void prep_genes(const float* __restrict__ W,
                           const float* __restrict__ px_o,
                           const float* __restrict__ eta,
                           const float* __restrict__ beta,
                           unsigned short* __restrict__ rhB,
                           float* __restrict__ lsp1c,
                           float* __restrict__ lsn2,
                           float* __restrict__ eps) {
    int idx = blockIdx.x * 256 + threadIdx.x;   // Gn*64 total, exact
    int g = idx >> 6, l = idx & 63;
    int j = g & 63, gb = g & ~63;
    int c = (j & 3) * 16 + (j >> 2);            // permuted MFMA column
    float bsp = softplus_precise(beta[g]);
    rhB[(size_t)(gb + c) * 64 + l] = f2bf(bsp * softplus_precise(W[idx]));
    if (idx < Gn) {
        eps[idx] = softplus_precise(eta[idx]);
        float o = px_o[idx];
        lsp1c[idx] = (-softplus_precise(-o) - 1.0f) * RLN2;
        lsn2[idx]  = -softplus_precise(o) * RLN2;
    }
}

__global__ void prep_spots(const float* __restrict__ V,
                           const int* __restrict__ ind_x,
                           unsigned short* __restrict__ vBg,
                           float* __restrict__ v64) {
    int idx = blockIdx.x * 256 + threadIdx.x;   // Bn*64 total, exact
    int b = idx >> 6, l = idx & 63;
    int s = ind_x[b];
    vBg[idx] = f2bf(softplus_precise(V[l * Sn + s]));
    if (idx < Bn) {
        int s2 = ind_x[idx];
        v64[idx] = softplus_precise(V[Ln * Sn + s2]);
    }
}

// prior: parallel, atomicAdd into out[Bn+1] (out pre-zeroed by memset)
__global__ void prior_kernel(const float* __restrict__ eta, float* __restrict__ out) {
    int idx = blockIdx.x * 256 + threadIdx.x;
    float s = 0.f;
    if (idx < Gn) {
        float e = eta[idx];
        s = 0.9189385332046727f + 0.5f * e * e;
    }
    #pragma unroll
    for (int off = 32; off; off >>= 1) s += __shfl_xor(s, off, 64);
    __shared__ float red[4];
    if ((threadIdx.x & 63) == 0) red[threadIdx.x >> 6] = s;
    __syncthreads();
    if (threadIdx.x == 0) atomicAdd(&out[Bn + 1], red[0] + red[1] + red[2] + red[3]);
}

// ---------- main kernel: uint8 x, raw-log2 epilogue, barrier-free ----------
//
// t2 = (s-0.5)log2 s - (rr-0.5)log2 rr + x*lsp1c + rr*lsn2 - lfact2[x]
// out[b] += -ln2 * sum_g t2

__global__ __launch_bounds__(256) void main_kernel(
    const unsigned char*  __restrict__ x8,
    const unsigned short* __restrict__ rhB,
    const unsigned short* __restrict__ vBg,
    const float*          __restrict__ v64,
    const float*          __restrict__ lsp1cg,
    const float*          __restrict__ lsn2g,
    const float*          __restrict__ epsg,
    float*                __restrict__ out) {
    __shared__ float lfact2[100];   // lgamma(x+1)/ln2

    const int tid = threadIdx.x;
    if (tid < 100) lfact2[tid] = lgamma_pos8((float)tid + 1.0f) * RLN2;
    __syncthreads();   // no VMEM in flight yet

    const int g0 = blockIdx.x * 64;
    const int b0 = blockIdx.y * 64;
    const int wave = tid >> 6, lane = tid & 63;
    const int quad = lane >> 4, ln = lane & 15;
    const int mrow  = wave * 16 + ln;              // A-fragment m index
    const int brow0 = b0 + wave * 16 + quad * 4;   // C rows for this lane

    // B fragments first (MFMA waits only on these + A), x last
    const unsigned short* bPtr = rhB + (size_t)(g0 + ln) * 64 + quad * 8;
    bf16x8 bf_[4][2];
    #pragma unroll
    for (int nb = 0; nb < 4; nb++) {
        bf_[nb][0] = *(const bf16x8*)(bPtr + nb * 1024);
        bf_[nb][1] = *(const bf16x8*)(bPtr + nb * 1024 + 32);
    }
    const unsigned short* aPtr = vBg + (size_t)(b0 + mrow) * 64 + quad * 8;
    bf16x8 af0 = *(const bf16x8*)(aPtr);
    bf16x8 af1 = *(const bf16x8*)(aPtr + 32);

    const float4 lsp1q = *(const float4*)(lsp1cg + g0 + ln * 4);
    const float4 lsn2q = *(const float4*)(lsn2g  + g0 + ln * 4);
    const float4 epsq  = *(const float4*)(epsg   + g0 + ln * 4);
    const float4 vq    = *(const float4*)(v64 + brow0);

    // x: 4 dword loads (4 packed genes per row), 4x fewer bytes than int32
    unsigned int xw[4];
    #pragma unroll
    for (int r = 0; r < 4; r++)
        xw[r] = *(const unsigned int*)(x8 + (size_t)(brow0 + r) * Gn + g0 + ln * 4);

    f32x4 acc[4];
    #pragma unroll
    for (int nb = 0; nb < 4; nb++) acc[nb] = (f32x4){0.f, 0.f, 0.f, 0.f};
    #pragma unroll
    for (int nb = 0; nb < 4; nb++) {
        acc[nb] = __builtin_amdgcn_mfma_f32_16x16x32_bf16(af0, bf_[nb][0], acc[nb], 0, 0, 0);
        acc[nb] = __builtin_amdgcn_mfma_f32_16x16x32_bf16(af1, bf_[nb][1], acc[nb], 0, 0, 0);
    }

    const float vvr[4]   = {vq.x, vq.y, vq.z, vq.w};
    const float lsp1v[4] = {lsp1q.x, lsp1q.y, lsp1q.z, lsp1q.w};
    const float lsn2v[4] = {lsn2q.x, lsn2q.y, lsn2q.z, lsn2q.w};
    const float ev4[4]   = {epsq.x, epsq.y, epsq.z, epsq.w};

    float rowpart[4] = {0.f, 0.f, 0.f, 0.f};
    #pragma unroll
    for (int nb = 0; nb < 4; nb++) {
        #pragma unroll
        for (int r = 0; r < 4; r++) {
            // acc[nb][r] = column nb*16+ln = gene g0+ln*4+nb (permuted B)
            const float rr = fmaf(ev4[nb], vvr[r], acc[nb][r]);
            const unsigned int xi = (xw[r] >> (8 * nb)) & 0xffu;
            const float xf = (float)xi;
            const float s  = rr + xf;
            const float ls = raw_log2(s);
            const float lr = raw_log2(rr);
            float u = fmaf(xf, lsp1v[nb], -lfact2[xi]);
            u = fmaf(rr, lsn2v[nb], u);
            u = fmaf(0.5f - rr, lr, u);
            u = fmaf(s - 0.5f, ls, u);
            rowpart[r] += u;
        }
    }

    // reduce over the 16 gene-lanes of each quad, one atomic per row
    #pragma unroll
    for (int r = 0; r < 4; r++) {
        float v = rowpart[r];
        v += __shfl_xor(v, 1, 64);
        v += __shfl_xor(v, 2, 64);
        v += __shfl_xor(v, 4, 64);
        v += __shfl_xor(v, 8, 64);
        if (ln == 0) atomicAdd(&out[brow0 + r], -LN2 * v);
    }
}

// ---------- launch ----------

extern "C" void kernel_launch(void* const* d_in, const int* in_sizes, int n_in,
                              void* d_out, int out_size, void* d_ws, size_t ws_size,
                              hipStream_t stream) {
    const int*   x     = (const int*)d_in[0];
    const int*   ind_x = (const int*)d_in[2];
    const float* W     = (const float*)d_in[3];
    const float* px_o  = (const float*)d_in[4];
    const float* eta   = (const float*)d_in[5];
    const float* V     = (const float*)d_in[6];
    const float* beta  = (const float*)d_in[7];
    float* out = (float*)d_out;

    // ws layout (bytes):
    char* wsb = (char*)d_ws;
    unsigned short* rhB   = (unsigned short*)(wsb);                   // Gn*64*2 = 2,048,000
    unsigned short* vBg   = (unsigned short*)(wsb + 2048000);         // Bn*64*2 =   524,288
    float*          v64   = (float*)(wsb + 2572288);                  // Bn*4    =    16,384
    float*          lsp1c = (float*)(wsb + 2588672);                  // Gn*4
    float*          lsn2  = (float*)(wsb + 2652672);                  // Gn*4
    float*          eps   = (float*)(wsb + 2716672);                  // Gn*4
    unsigned char*  x8    = (unsigned char*)(wsb + 4000000);          // Bn*Gn = 65,536,000

    // zero loss accumulators AND the two scalar slots
    hipMemsetAsync(d_out, 0, (Bn + 2) * sizeof(float), stream);

    pack_x<<<(Bn * Gn) / 4096, 256, 0, stream>>>(x, (unsigned int*)x8);
    prep_genes<<<(Gn * 64) / 256, 256, 0, stream>>>(W, px_o, eta, beta, rhB, lsp1c, lsn2, eps);
    prep_spots<<<(Bn * 64) / 256, 256, 0, stream>>>(V, ind_x, vBg, v64);
    prior_kernel<<<(Gn + 255) / 256, 256, 0, stream>>>(eta, out);

    dim3 grid(Gn / 64, Bn / 64);   // 250 x 64
    main_kernel<<<grid, 256, 0, stream>>>(x8, rhB, vBg, v64, lsp1c, lsn2, eps, out);
}